// Round 15
// baseline (247.963 us; speedup 1.0000x reference)
//
#include <hip/hip_runtime.h>
#include <hip/hip_bf16.h>

#define NNODES 20000
#define NEDGES 160000
#define BQ     64
#define FTEXT  300
#define KPAD1  320          // FTEXT padded to multiple of 32
#define HIDDIM 1024
#define OUTDIM 1664

typedef __attribute__((ext_vector_type(8))) short short8;
typedef __attribute__((ext_vector_type(4))) float floatx4;

__device__ inline unsigned short f2bf(float f) {
    union { float f; unsigned int u; } v; v.f = f;
    unsigned int r = v.u + 0x7FFF + ((v.u >> 16) & 1);   // RNE
    return (unsigned short)(r >> 16);
}
__device__ inline float bf2f(unsigned short h) {
    union { unsigned int u; float f; } v; v.u = ((unsigned int)h) << 16;
    return v.f;
}

// ---------------- degree + count ----------------
__global__ void degcnt_kernel(const int* __restrict__ dst, const float* __restrict__ w,
                              float* __restrict__ deg, int* __restrict__ cnt, int E) {
    int e = blockIdx.x * blockDim.x + threadIdx.x;
    if (e < E) {
        int d = dst[e];
        atomicAdd(&deg[d], w[e]);
        atomicAdd(&cnt[d], 1);
    }
}

// ---------------- CSR scan ----------------
__global__ __launch_bounds__(1024) void scan_kernel(const int* __restrict__ cnt,
                                                    int* __restrict__ row_start, int N) {
    __shared__ int partial[1024];
    const int CH = 20;
    int t = threadIdx.x;
    int begin = t * CH;
    int nloc = N - begin; if (nloc > CH) nloc = CH; if (nloc < 0) nloc = 0;
    int vals[CH];
    int s = 0;
    if (nloc == CH) {
        #pragma unroll
        for (int i = 0; i < CH / 4; i++) {
            int4 v = ((const int4*)(cnt + begin))[i];
            vals[i*4+0] = v.x; vals[i*4+1] = v.y; vals[i*4+2] = v.z; vals[i*4+3] = v.w;
            s += v.x + v.y + v.z + v.w;
        }
    } else {
        for (int i = 0; i < nloc; i++) { vals[i] = cnt[begin + i]; s += vals[i]; }
    }
    partial[t] = s;
    __syncthreads();
    for (int off = 1; off < 1024; off <<= 1) {
        int v = (t >= off) ? partial[t - off] : 0;
        __syncthreads();
        partial[t] += v;
        __syncthreads();
    }
    int run = (t == 0) ? 0 : partial[t - 1];
    for (int i = 0; i < nloc; i++) { row_start[begin + i] = run; run += vals[i]; }
    if (t == 1023) row_start[N] = partial[1023];
}

// fill dst-sorted edge arrays with INLINE norm
__global__ void fill_kernel(const int* __restrict__ dst, const int* __restrict__ src,
                            const float* __restrict__ w, const float* __restrict__ deg,
                            const int* __restrict__ row_start, int* __restrict__ cursor,
                            int* __restrict__ src_s, float* __restrict__ wnrm_s, int E) {
    int e = blockIdx.x * blockDim.x + threadIdx.x;
    if (e < E) {
        int d = dst[e], s = src[e];
        float dd = deg[d], ds = deg[s];
        float nv = (ds > 0.f ? rsqrtf(ds) : 0.f) * w[e] * (dd > 0.f ? rsqrtf(dd) : 0.f);
        int pos = row_start[d] + atomicAdd(&cursor[d], 1);
        src_s[pos] = s;
        wnrm_s[pos] = nv;
    }
}

// ---------------- aggNF[d, 0:320] (bf16, zero-padded) = sum w*nfb[src,:] -------
__global__ __launch_bounds__(256) void aggnf_kernel(const unsigned short* __restrict__ nfb,
        const int* __restrict__ row_start, const int* __restrict__ src_s,
        const float* __restrict__ wnrm_s, unsigned short* __restrict__ out) {
    int wave = threadIdx.x >> 6, lane = threadIdx.x & 63;
    int d = blockIdx.x * 4 + wave;
    int s0 = row_start[d], s1 = row_start[d + 1];
    float4 acc  = make_float4(0.f, 0.f, 0.f, 0.f);
    float4 acc2 = make_float4(0.f, 0.f, 0.f, 0.f);
    for (int base = s0; base < s1; base += 64) {
        int m = s1 - base; if (m > 64) m = 64;
        int   src_l = (lane < m) ? src_s[base + lane]  : 0;
        float w_l   = (lane < m) ? wnrm_s[base + lane] : 0.f;
        int sj = __shfl(src_l, 0);
        float wj = __shfl(w_l, 0);
        const ushort4* row = (const ushort4*)(nfb + (long)sj * FTEXT);
        ushort4 hv  = row[lane];
        ushort4 hv2 = make_ushort4(0, 0, 0, 0);
        if (lane < 11) hv2 = row[64 + lane];
        for (int j = 0; j < m; j++) {
            ushort4 nv  = make_ushort4(0, 0, 0, 0);
            ushort4 nv2 = make_ushort4(0, 0, 0, 0);
            float wn = 0.f;
            if (j + 1 < m) {
                int sn = __shfl(src_l, j + 1);
                wn = __shfl(w_l, j + 1);
                const ushort4* nrow = (const ushort4*)(nfb + (long)sn * FTEXT);
                nv = nrow[lane];
                if (lane < 11) nv2 = nrow[64 + lane];
            }
            acc.x  += bf2f(hv.x)  * wj; acc.y  += bf2f(hv.y)  * wj;
            acc.z  += bf2f(hv.z)  * wj; acc.w  += bf2f(hv.w)  * wj;
            acc2.x += bf2f(hv2.x) * wj; acc2.y += bf2f(hv2.y) * wj;
            acc2.z += bf2f(hv2.z) * wj; acc2.w += bf2f(hv2.w) * wj;
            hv = nv; hv2 = nv2; wj = wn;
        }
    }
    unsigned short* orow = out + (long)d * KPAD1;
    ushort4 o;
    o.x = f2bf(acc.x); o.y = f2bf(acc.y); o.z = f2bf(acc.z); o.w = f2bf(acc.w);
    ((ushort4*)orow)[lane] = o;
    if (lane < 16) {
        ushort4 o2 = make_ushort4(0, 0, 0, 0);
        if (lane < 11) {
            o2.x = f2bf(acc2.x); o2.y = f2bf(acc2.y);
            o2.z = f2bf(acc2.z); o2.w = f2bf(acc2.w);
        }
        ((ushort4*)orow)[64 + lane] = o2;
    }
}

// ---------------- all weight/input conversions in ONE kernel ------------------
#define W1N  (HIDDIM * KPAD1)
#define N1F4 (HIDDIM * OUTDIM / 4)
#define N2F4 (BQ * OUTDIM / 4)
#define N3F4 (NNODES * FTEXT / 4)
__global__ void cvt_all_kernel(const float* __restrict__ W1, unsigned short* __restrict__ W1bt,
                               const float* __restrict__ W2, unsigned short* __restrict__ W2b,
                               const float* __restrict__ img, unsigned short* __restrict__ imgb,
                               const float* __restrict__ nf, unsigned short* __restrict__ nfb) {
    int i = blockIdx.x * 256 + threadIdx.x;
    if (i < W1N) {
        int n = i / KPAD1, k = i % KPAD1;
        float v = (k < FTEXT) ? W1[(long)k * HIDDIM + n] : 0.f;
        W1bt[i] = f2bf(v);
        return;
    }
    i -= W1N;
    const float* in; unsigned short* outp; int j;
    if (i < N1F4)                    { in = W2;  outp = W2b;  j = i; }
    else if (i < N1F4 + N2F4)        { in = img; outp = imgb; j = i - N1F4; }
    else if (i < N1F4 + N2F4 + N3F4) { in = nf;  outp = nfb;  j = i - N1F4 - N2F4; }
    else return;
    float4 v = ((const float4*)in)[j];
    ushort4 o;
    o.x = f2bf(v.x); o.y = f2bf(v.y); o.z = f2bf(v.z); o.w = f2bf(v.w);
    ((ushort4*)outp)[j] = o;
}

// ---------------- Zt = bf16(Ztf)  +  cvec[b] = img[b,:].b2 --------------------
__global__ __launch_bounds__(256) void ztcvec_kernel(const float* __restrict__ Ztf,
        unsigned short* __restrict__ Zt, const float* __restrict__ img,
        const float* __restrict__ b2, float* __restrict__ cvec) {
    if (blockIdx.x < (BQ * HIDDIM) / 256) {
        int i = blockIdx.x * 256 + threadIdx.x;
        Zt[i] = f2bf(Ztf[i]);
    } else {
        int b = blockIdx.x - (BQ * HIDDIM) / 256;
        int l = threadIdx.x;
        float v = 0.f;
        for (int f = l; f < OUTDIM; f += 256) v += img[(long)b * OUTDIM + f] * b2[f];
        __shared__ float red[256];
        red[l] = v;
        __syncthreads();
        if (l < 64) {
            v = red[l] + red[l + 64] + red[l + 128] + red[l + 192];
            for (int off = 32; off > 0; off >>= 1) v += __shfl_down(v, off);
            if (l == 0) cvec[b] = v;
        }
    }
}

// ---------------- bf16 MFMA GEMM (used for Zt only now) -----------------------
template<int EPI, int OUT_BF16, int ATOMIC, int NT>
__global__ __launch_bounds__(256) void mfma_gemm(
        const unsigned short* __restrict__ A, const unsigned short* __restrict__ B,
        const float* __restrict__ bias, void* __restrict__ Cv,
        int M, int N, int K, int ldc) {
    constexpr int CT = NT / 16;
    __shared__ unsigned short As[128][40];
    __shared__ unsigned short Bs[NT][40];
    int t = threadIdx.x;
    int m0 = blockIdx.y * 128;
    int n0 = blockIdx.x * NT;
    int klen = K / gridDim.z;
    int kbeg = blockIdx.z * klen;
    int wave = t >> 6, lane = t & 63;
    int lm = lane & 15, lq = lane >> 4;
    floatx4 acc[2][CT] = {};
    for (int k0 = kbeg; k0 < kbeg + klen; k0 += 32) {
        #pragma unroll
        for (int p = 0; p < 2; p++) {
            int idx = p * 256 + t;
            int r = idx >> 2, c8 = (idx & 3) * 8;
            uint4 v = make_uint4(0, 0, 0, 0);
            int gm = m0 + r;
            if (gm < M) v = *(const uint4*)(A + (long)gm * K + k0 + c8);
            *(uint4*)&As[r][c8] = v;
        }
        #pragma unroll
        for (int p = 0; p < NT / 64; p++) {
            int idx = p * 256 + t;
            int r = idx >> 2, c8 = (idx & 3) * 8;
            uint4 v = *(const uint4*)(B + (long)(n0 + r) * K + k0 + c8);
            *(uint4*)&Bs[r][c8] = v;
        }
        __syncthreads();
        short8 a[2], b[CT];
        #pragma unroll
        for (int rt = 0; rt < 2; rt++)
            a[rt] = *(const short8*)&As[wave * 32 + rt * 16 + lm][lq * 8];
        #pragma unroll
        for (int ct = 0; ct < CT; ct++)
            b[ct] = *(const short8*)&Bs[ct * 16 + lm][lq * 8];
        #pragma unroll
        for (int rt = 0; rt < 2; rt++)
            #pragma unroll
            for (int ct = 0; ct < CT; ct++)
                acc[rt][ct] = __builtin_amdgcn_mfma_f32_16x16x32_bf16(
                    a[rt], b[ct], acc[rt][ct], 0, 0, 0);
        __syncthreads();
    }
    #pragma unroll
    for (int rt = 0; rt < 2; rt++) {
        #pragma unroll
        for (int r = 0; r < 4; r++) {
            int gm = m0 + wave * 32 + rt * 16 + lq * 4 + r;
            if (gm >= M) continue;
            #pragma unroll
            for (int ct = 0; ct < CT; ct++) {
                int gn = n0 + ct * 16 + lm;
                float v = acc[rt][ct][r];
                if (EPI) { v += bias[gn]; v = v >= 0.f ? v : 0.2f * v; }
                if (OUT_BF16)      ((unsigned short*)Cv)[(long)gm * ldc + gn] = f2bf(v);
                else if (ATOMIC)   atomicAdd((float*)Cv + (long)gm * ldc + gn, v);
                else               ((float*)Cv)[(long)gm * ldc + gn] = v;
            }
        }
    }
}

// ---------------- FUSED: x-tile = leaky(aggNF@W1^T+b1); Y += x-tile @ Zt^T -----
// Grid (157 m, 8 n-slice): x-fastest dispatch => co-resident blocks have
// DIFFERENT m0 -> atomic targets disjoint (R14's grid had 8 blocks hammering
// the same 32KB Y tile). K-loop = measured-best gemm1 body (BK=32, [128][40],
// a[2]/b[8]). LDS: xs 34.8 KB with As/Bs unioned inside -> 4 blocks/CU.
__global__ __launch_bounds__(256) void xy_gemm(
        const unsigned short* __restrict__ aggNF, const unsigned short* __restrict__ W1bt,
        const float* __restrict__ b1, const unsigned short* __restrict__ Zt,
        float* __restrict__ Y, int M) {
    __shared__ unsigned short smem[128 * 136];           // 34816 B
    unsigned short (*As)[40]  = (unsigned short (*)[40])smem;          // 128x40
    unsigned short (*Bs)[40]  = (unsigned short (*)[40])(smem + 5120); // 128x40
    unsigned short (*xs)[136] = (unsigned short (*)[136])smem;         // reuse
    int t = threadIdx.x;
    int wave = t >> 6, lane = t & 63;
    int lm = lane & 15, lq = lane >> 4;
    int m0 = blockIdx.x * 128;     // m on x: co-scheduled blocks differ in m0
    int n0 = blockIdx.y * 128;     // n-slice on y
    floatx4 acc[2][8] = {};
    // ---- GEMM1: x_tile = aggNF[m0:,:] @ W1bt[n0:,:]^T   (K=320, BK=32) ----
    for (int k0 = 0; k0 < KPAD1; k0 += 32) {
        #pragma unroll
        for (int p = 0; p < 2; p++) {        // A tile: 128x32 shorts = 512 uint4
            int idx = p * 256 + t;
            int r = idx >> 2, c8 = (idx & 3) * 8;
            uint4 v = make_uint4(0, 0, 0, 0);
            int gm = m0 + r;
            if (gm < M) v = *(const uint4*)(aggNF + (long)gm * KPAD1 + k0 + c8);
            *(uint4*)&As[r][c8] = v;
        }
        #pragma unroll
        for (int p = 0; p < 2; p++) {        // B tile: 128x32 shorts = 512 uint4
            int idx = p * 256 + t;
            int r = idx >> 2, c8 = (idx & 3) * 8;
            uint4 v = *(const uint4*)(W1bt + (long)(n0 + r) * KPAD1 + k0 + c8);
            *(uint4*)&Bs[r][c8] = v;
        }
        __syncthreads();
        short8 a[2], b[8];
        #pragma unroll
        for (int rt = 0; rt < 2; rt++)
            a[rt] = *(const short8*)&As[wave * 32 + rt * 16 + lm][lq * 8];
        #pragma unroll
        for (int ct = 0; ct < 8; ct++)
            b[ct] = *(const short8*)&Bs[ct * 16 + lm][lq * 8];
        #pragma unroll
        for (int rt = 0; rt < 2; rt++)
            #pragma unroll
            for (int ct = 0; ct < 8; ct++)
                acc[rt][ct] = __builtin_amdgcn_mfma_f32_16x16x32_bf16(
                    a[rt], b[ct], acc[rt][ct], 0, 0, 0);
        __syncthreads();   // all waves done with As/Bs -> safe to reuse as xs
    }
    // ---- epilogue 1: bias + leaky, C-layout -> xs (A-frag-readable) ----
    #pragma unroll
    for (int ct = 0; ct < 8; ct++) {
        int col = ct * 16 + lm;
        float bv = b1[n0 + col];
        #pragma unroll
        for (int rt = 0; rt < 2; rt++) {
            #pragma unroll
            for (int r = 0; r < 4; r++) {
                float v = acc[rt][ct][r] + bv;
                v = v >= 0.f ? v : 0.2f * v;
                xs[wave * 32 + rt * 16 + lq * 4 + r][col] = f2bf(v);
            }
        }
    }
    __syncthreads();
    // ---- GEMM2: Y[m0:,:] += x_tile @ Zt[:, n0:n0+128]^T ----
    floatx4 yacc[2][4] = {};
    #pragma unroll
    for (int kk = 0; kk < 4; kk++) {
        short8 a0 = *(const short8*)&xs[wave * 32 + lm][kk * 32 + lq * 8];
        short8 a1 = *(const short8*)&xs[wave * 32 + 16 + lm][kk * 32 + lq * 8];
        #pragma unroll
        for (int bt = 0; bt < 4; bt++) {
            short8 b = *(const short8*)(Zt + (long)(bt * 16 + lm) * HIDDIM
                                            + n0 + kk * 32 + lq * 8);
            yacc[0][bt] = __builtin_amdgcn_mfma_f32_16x16x32_bf16(a0, b, yacc[0][bt], 0, 0, 0);
            yacc[1][bt] = __builtin_amdgcn_mfma_f32_16x16x32_bf16(a1, b, yacc[1][bt], 0, 0, 0);
        }
    }
    #pragma unroll
    for (int rt = 0; rt < 2; rt++) {
        #pragma unroll
        for (int bt = 0; bt < 4; bt++) {
            #pragma unroll
            for (int r = 0; r < 4; r++) {
                int gm = m0 + wave * 32 + rt * 16 + lq * 4 + r;
                if (gm < M) atomicAdd(&Y[(long)gm * 64 + bt * 16 + lm], yacc[rt][bt][r]);
            }
        }
    }
}

// ---------------- out[b,d] = sum_{e:dst=d} w*Y[src,b] + c[b] ------------------
__global__ __launch_bounds__(256) void outagg_kernel(const float* __restrict__ Y,
        const int* __restrict__ row_start, const int* __restrict__ src_s,
        const float* __restrict__ wnrm_s, const float* __restrict__ c,
        float* __restrict__ out, int N) {
    __shared__ float tile[4][68];
    int d0 = blockIdx.x * 4;
    int t = threadIdx.x;
    int wave = t >> 6, lane = t & 63;
    int d = d0 + wave;
    int s0 = row_start[d], s1 = row_start[d + 1];
    float acc = 0.f;
    for (int base = s0; base < s1; base += 64) {
        int m = s1 - base; if (m > 64) m = 64;
        int   src_l = (lane < m) ? src_s[base + lane]  : 0;
        float w_l   = (lane < m) ? wnrm_s[base + lane] : 0.f;
        int sj = __shfl(src_l, 0);
        float wj = __shfl(w_l, 0);
        float yv = Y[(long)sj * 64 + lane];
        for (int j = 0; j < m; j++) {
            float yn = 0.f, wn = 0.f;
            if (j + 1 < m) {
                int sn = __shfl(src_l, j + 1);
                wn = __shfl(w_l, j + 1);
                yn = Y[(long)sn * 64 + lane];
            }
            acc += wj * yv;
            yv = yn; wj = wn;
        }
    }
    tile[wave][lane] = acc + c[lane];
    __syncthreads();
    int b = t >> 2, j = t & 3;
    out[(long)b * N + d0 + j] = tile[j][b];
}

extern "C" void kernel_launch(void* const* d_in, const int* in_sizes, int n_in,
                              void* d_out, int out_size, void* d_ws, size_t ws_size,
                              hipStream_t stream) {
    const float* img_feat      = (const float*)d_in[0];
    const float* node_features = (const float*)d_in[1];
    const int*   edge_src      = (const int*)d_in[2];
    const int*   edge_dst      = (const int*)d_in[3];
    const float* edge_weight   = (const float*)d_in[4];
    const float* W1            = (const float*)d_in[5];
    const float* b1            = (const float*)d_in[6];
    const float* W2            = (const float*)d_in[7];
    const float* b2            = (const float*)d_in[8];
    float* out = (float*)d_out;

    const int N = NNODES, E = NEDGES;

    char* ws = (char*)d_ws;
    size_t off = 0;
    auto alloc = [&](size_t bytes) -> void* {
        void* p = ws + off;
        off = (off + bytes + 255) & ~(size_t)255;
        return p;
    };
    // ---- zero-initialized region (single memset) ----
    float*          deg       = (float*)alloc((size_t)N * 4);
    int*            cnt       = (int*)alloc((size_t)N * 4);
    int*            cursor    = (int*)alloc((size_t)N * 4);
    float*          Ztf       = (float*)alloc((size_t)BQ * HIDDIM * 4);
    float*          Y         = (float*)alloc((size_t)N * BQ * 4);
    size_t zero_bytes = off;
    // ---- rest ----
    int*            row_start = (int*)alloc((size_t)(N + 1) * 4);
    int*            src_s     = (int*)alloc((size_t)E * 4);
    float*          wnrm_s    = (float*)alloc((size_t)E * 4);
    unsigned short* aggNF     = (unsigned short*)alloc((size_t)N * KPAD1 * 2);
    unsigned short* W1bt      = (unsigned short*)alloc((size_t)HIDDIM * KPAD1 * 2);
    unsigned short* W2b       = (unsigned short*)alloc((size_t)HIDDIM * OUTDIM * 2);
    unsigned short* imgb      = (unsigned short*)alloc((size_t)BQ * OUTDIM * 2);
    unsigned short* nfb       = (unsigned short*)alloc((size_t)N * FTEXT * 2);
    unsigned short* Zt        = (unsigned short*)alloc((size_t)BQ * HIDDIM * 2);
    float*          cvec      = (float*)alloc((size_t)BQ * 4);

    hipMemsetAsync(ws, 0, zero_bytes, stream);

    int eb = (E + 255) / 256;
    degcnt_kernel<<<eb, 256, 0, stream>>>(edge_dst, edge_weight, deg, cnt, E);
    scan_kernel<<<1, 1024, 0, stream>>>(cnt, row_start, N);
    fill_kernel<<<eb, 256, 0, stream>>>(edge_dst, edge_src, edge_weight, deg, row_start,
                                        cursor, src_s, wnrm_s, E);

    cvt_all_kernel<<<(W1N + (N1F4 + N2F4 + N3F4) + 255) / 256, 256, 0, stream>>>(
        W1, W1bt, W2, W2b, img_feat, imgb, node_features, nfb);

    // Ztf = img @ W2^T  [64 x 1024]  (MFMA, split-K=13, fp32 atomic)
    mfma_gemm<0, 0, 1, 64><<<dim3(HIDDIM / 64, 1, 13), 256, 0, stream>>>(
        imgb, W2b, nullptr, Ztf, BQ, HIDDIM, OUTDIM, HIDDIM);
    ztcvec_kernel<<<(BQ * HIDDIM) / 256 + BQ, 256, 0, stream>>>(Ztf, Zt, img_feat, b2, cvec);

    // aggNF = bf16(A @ nfb), k-padded
    aggnf_kernel<<<N / 4, 256, 0, stream>>>(nfb, row_start, src_s, wnrm_s, aggNF);

    // FUSED: Y += leaky(aggNF @ W1 + b1) @ Zt^T   (x stays on-chip)
    xy_gemm<<<dim3((N + 127) / 128, HIDDIM / 128), 256, 0, stream>>>(
        aggNF, W1bt, b1, Zt, Y, N);

    outagg_kernel<<<N / 4, 256, 0, stream>>>(Y, row_start, src_s, wnrm_s, cvec, out, N);
}

// Round 16
// 244.038 us; speedup vs baseline: 1.0161x; 1.0161x over previous
//
#include <hip/hip_runtime.h>
#include <hip/hip_bf16.h>

#define NNODES 20000
#define NEDGES 160000
#define BQ     64
#define FTEXT  300
#define KPAD1  320          // FTEXT padded to multiple of 32
#define HIDDIM 1024
#define OUTDIM 1664

typedef __attribute__((ext_vector_type(8))) short short8;
typedef __attribute__((ext_vector_type(4))) float floatx4;

__device__ inline unsigned short f2bf(float f) {
    union { float f; unsigned int u; } v; v.f = f;
    unsigned int r = v.u + 0x7FFF + ((v.u >> 16) & 1);   // RNE
    return (unsigned short)(r >> 16);
}
__device__ inline float bf2f(unsigned short h) {
    union { unsigned int u; float f; } v; v.u = ((unsigned int)h) << 16;
    return v.f;
}

// ---------------- degree + count ----------------
__global__ void degcnt_kernel(const int* __restrict__ dst, const float* __restrict__ w,
                              float* __restrict__ deg, int* __restrict__ cnt, int E) {
    int e = blockIdx.x * blockDim.x + threadIdx.x;
    if (e < E) {
        int d = dst[e];
        atomicAdd(&deg[d], w[e]);
        atomicAdd(&cnt[d], 1);
    }
}

// ---------------- CSR scan ----------------
__global__ __launch_bounds__(1024) void scan_kernel(const int* __restrict__ cnt,
                                                    int* __restrict__ row_start, int N) {
    __shared__ int partial[1024];
    const int CH = 20;
    int t = threadIdx.x;
    int begin = t * CH;
    int nloc = N - begin; if (nloc > CH) nloc = CH; if (nloc < 0) nloc = 0;
    int vals[CH];
    int s = 0;
    if (nloc == CH) {
        #pragma unroll
        for (int i = 0; i < CH / 4; i++) {
            int4 v = ((const int4*)(cnt + begin))[i];
            vals[i*4+0] = v.x; vals[i*4+1] = v.y; vals[i*4+2] = v.z; vals[i*4+3] = v.w;
            s += v.x + v.y + v.z + v.w;
        }
    } else {
        for (int i = 0; i < nloc; i++) { vals[i] = cnt[begin + i]; s += vals[i]; }
    }
    partial[t] = s;
    __syncthreads();
    for (int off = 1; off < 1024; off <<= 1) {
        int v = (t >= off) ? partial[t - off] : 0;
        __syncthreads();
        partial[t] += v;
        __syncthreads();
    }
    int run = (t == 0) ? 0 : partial[t - 1];
    for (int i = 0; i < nloc; i++) { row_start[begin + i] = run; run += vals[i]; }
    if (t == 1023) row_start[N] = partial[1023];
}

// fill dst-sorted edge arrays with INLINE norm
__global__ void fill_kernel(const int* __restrict__ dst, const int* __restrict__ src,
                            const float* __restrict__ w, const float* __restrict__ deg,
                            const int* __restrict__ row_start, int* __restrict__ cursor,
                            int* __restrict__ src_s, float* __restrict__ wnrm_s, int E) {
    int e = blockIdx.x * blockDim.x + threadIdx.x;
    if (e < E) {
        int d = dst[e], s = src[e];
        float dd = deg[d], ds = deg[s];
        float nv = (ds > 0.f ? rsqrtf(ds) : 0.f) * w[e] * (dd > 0.f ? rsqrtf(dd) : 0.f);
        int pos = row_start[d] + atomicAdd(&cursor[d], 1);
        src_s[pos] = s;
        wnrm_s[pos] = nv;
    }
}

// ---------------- aggNF[d, 0:320] (bf16, zero-padded) = sum w*nfb[src,:] -------
__global__ __launch_bounds__(256) void aggnf_kernel(const unsigned short* __restrict__ nfb,
        const int* __restrict__ row_start, const int* __restrict__ src_s,
        const float* __restrict__ wnrm_s, unsigned short* __restrict__ out) {
    int wave = threadIdx.x >> 6, lane = threadIdx.x & 63;
    int d = blockIdx.x * 4 + wave;
    int s0 = row_start[d], s1 = row_start[d + 1];
    float4 acc  = make_float4(0.f, 0.f, 0.f, 0.f);
    float4 acc2 = make_float4(0.f, 0.f, 0.f, 0.f);
    for (int base = s0; base < s1; base += 64) {
        int m = s1 - base; if (m > 64) m = 64;
        int   src_l = (lane < m) ? src_s[base + lane]  : 0;
        float w_l   = (lane < m) ? wnrm_s[base + lane] : 0.f;
        int sj = __shfl(src_l, 0);
        float wj = __shfl(w_l, 0);
        const ushort4* row = (const ushort4*)(nfb + (long)sj * FTEXT);
        ushort4 hv  = row[lane];
        ushort4 hv2 = make_ushort4(0, 0, 0, 0);
        if (lane < 11) hv2 = row[64 + lane];
        for (int j = 0; j < m; j++) {
            ushort4 nv  = make_ushort4(0, 0, 0, 0);
            ushort4 nv2 = make_ushort4(0, 0, 0, 0);
            float wn = 0.f;
            if (j + 1 < m) {
                int sn = __shfl(src_l, j + 1);
                wn = __shfl(w_l, j + 1);
                const ushort4* nrow = (const ushort4*)(nfb + (long)sn * FTEXT);
                nv = nrow[lane];
                if (lane < 11) nv2 = nrow[64 + lane];
            }
            acc.x  += bf2f(hv.x)  * wj; acc.y  += bf2f(hv.y)  * wj;
            acc.z  += bf2f(hv.z)  * wj; acc.w  += bf2f(hv.w)  * wj;
            acc2.x += bf2f(hv2.x) * wj; acc2.y += bf2f(hv2.y) * wj;
            acc2.z += bf2f(hv2.z) * wj; acc2.w += bf2f(hv2.w) * wj;
            hv = nv; hv2 = nv2; wj = wn;
        }
    }
    unsigned short* orow = out + (long)d * KPAD1;
    ushort4 o;
    o.x = f2bf(acc.x); o.y = f2bf(acc.y); o.z = f2bf(acc.z); o.w = f2bf(acc.w);
    ((ushort4*)orow)[lane] = o;
    if (lane < 16) {
        ushort4 o2 = make_ushort4(0, 0, 0, 0);
        if (lane < 11) {
            o2.x = f2bf(acc2.x); o2.y = f2bf(acc2.y);
            o2.z = f2bf(acc2.z); o2.w = f2bf(acc2.w);
        }
        ((ushort4*)orow)[64 + lane] = o2;
    }
}

// ---------------- all weight/input conversions in ONE kernel ------------------
#define W1N  (HIDDIM * KPAD1)
#define N1F4 (HIDDIM * OUTDIM / 4)
#define N2F4 (BQ * OUTDIM / 4)
#define N3F4 (NNODES * FTEXT / 4)
__global__ void cvt_all_kernel(const float* __restrict__ W1, unsigned short* __restrict__ W1bt,
                               const float* __restrict__ W2, unsigned short* __restrict__ W2b,
                               const float* __restrict__ img, unsigned short* __restrict__ imgb,
                               const float* __restrict__ nf, unsigned short* __restrict__ nfb) {
    int i = blockIdx.x * 256 + threadIdx.x;
    if (i < W1N) {
        int n = i / KPAD1, k = i % KPAD1;
        float v = (k < FTEXT) ? W1[(long)k * HIDDIM + n] : 0.f;
        W1bt[i] = f2bf(v);
        return;
    }
    i -= W1N;
    const float* in; unsigned short* outp; int j;
    if (i < N1F4)                    { in = W2;  outp = W2b;  j = i; }
    else if (i < N1F4 + N2F4)        { in = img; outp = imgb; j = i - N1F4; }
    else if (i < N1F4 + N2F4 + N3F4) { in = nf;  outp = nfb;  j = i - N1F4 - N2F4; }
    else return;
    float4 v = ((const float4*)in)[j];
    ushort4 o;
    o.x = f2bf(v.x); o.y = f2bf(v.y); o.z = f2bf(v.z); o.w = f2bf(v.w);
    ((ushort4*)outp)[j] = o;
}

// ---------------- Zt = bf16(Ztf)  +  cvec[b] = img[b,:].b2 --------------------
__global__ __launch_bounds__(256) void ztcvec_kernel(const float* __restrict__ Ztf,
        unsigned short* __restrict__ Zt, const float* __restrict__ img,
        const float* __restrict__ b2, float* __restrict__ cvec) {
    if (blockIdx.x < (BQ * HIDDIM) / 256) {
        int i = blockIdx.x * 256 + threadIdx.x;
        Zt[i] = f2bf(Ztf[i]);
    } else {
        int b = blockIdx.x - (BQ * HIDDIM) / 256;
        int l = threadIdx.x;
        float v = 0.f;
        for (int f = l; f < OUTDIM; f += 256) v += img[(long)b * OUTDIM + f] * b2[f];
        __shared__ float red[256];
        red[l] = v;
        __syncthreads();
        if (l < 64) {
            v = red[l] + red[l + 64] + red[l + 128] + red[l + 192];
            for (int off = 32; off > 0; off >>= 1) v += __shfl_down(v, off);
            if (l == 0) cvec[b] = v;
        }
    }
}

// ---------------- bf16 MFMA GEMM (used for Zt only now) -----------------------
template<int EPI, int OUT_BF16, int ATOMIC, int NT>
__global__ __launch_bounds__(256) void mfma_gemm(
        const unsigned short* __restrict__ A, const unsigned short* __restrict__ B,
        const float* __restrict__ bias, void* __restrict__ Cv,
        int M, int N, int K, int ldc) {
    constexpr int CT = NT / 16;
    __shared__ unsigned short As[128][40];
    __shared__ unsigned short Bs[NT][40];
    int t = threadIdx.x;
    int m0 = blockIdx.y * 128;
    int n0 = blockIdx.x * NT;
    int klen = K / gridDim.z;
    int kbeg = blockIdx.z * klen;
    int wave = t >> 6, lane = t & 63;
    int lm = lane & 15, lq = lane >> 4;
    floatx4 acc[2][CT] = {};
    for (int k0 = kbeg; k0 < kbeg + klen; k0 += 32) {
        #pragma unroll
        for (int p = 0; p < 2; p++) {
            int idx = p * 256 + t;
            int r = idx >> 2, c8 = (idx & 3) * 8;
            uint4 v = make_uint4(0, 0, 0, 0);
            int gm = m0 + r;
            if (gm < M) v = *(const uint4*)(A + (long)gm * K + k0 + c8);
            *(uint4*)&As[r][c8] = v;
        }
        #pragma unroll
        for (int p = 0; p < NT / 64; p++) {
            int idx = p * 256 + t;
            int r = idx >> 2, c8 = (idx & 3) * 8;
            uint4 v = *(const uint4*)(B + (long)(n0 + r) * K + k0 + c8);
            *(uint4*)&Bs[r][c8] = v;
        }
        __syncthreads();
        short8 a[2], b[CT];
        #pragma unroll
        for (int rt = 0; rt < 2; rt++)
            a[rt] = *(const short8*)&As[wave * 32 + rt * 16 + lm][lq * 8];
        #pragma unroll
        for (int ct = 0; ct < CT; ct++)
            b[ct] = *(const short8*)&Bs[ct * 16 + lm][lq * 8];
        #pragma unroll
        for (int rt = 0; rt < 2; rt++)
            #pragma unroll
            for (int ct = 0; ct < CT; ct++)
                acc[rt][ct] = __builtin_amdgcn_mfma_f32_16x16x32_bf16(
                    a[rt], b[ct], acc[rt][ct], 0, 0, 0);
        __syncthreads();
    }
    #pragma unroll
    for (int rt = 0; rt < 2; rt++) {
        #pragma unroll
        for (int r = 0; r < 4; r++) {
            int gm = m0 + wave * 32 + rt * 16 + lq * 4 + r;
            if (gm >= M) continue;
            #pragma unroll
            for (int ct = 0; ct < CT; ct++) {
                int gn = n0 + ct * 16 + lm;
                float v = acc[rt][ct][r];
                if (EPI) { v += bias[gn]; v = v >= 0.f ? v : 0.2f * v; }
                if (OUT_BF16)      ((unsigned short*)Cv)[(long)gm * ldc + gn] = f2bf(v);
                else if (ATOMIC)   atomicAdd((float*)Cv + (long)gm * ldc + gn, v);
                else               ((float*)Cv)[(long)gm * ldc + gn] = v;
            }
        }
    }
}

// ---------------- FUSED: x-tile = leaky(aggNF@W1^T+b1); Y += x-tile @ Zt^T -----
// XCD-aware swizzle: round-robin dispatch puts block b on XCD b%8 (m09). Decode
// xcd=b&7, grp=b>>3, slot=grp>>3, n=grp&7, m=xcd+8*slot  =>  all 8 n-slices of
// one m-strip run back-to-back on ONE XCD -> its aggNF A-strip is fetched into
// that XCD's L2 once (R14/R15 cross-XCD layouts re-fetched it ~4x: FETCH 50MB
// vs 13.5MB unique). K-loop = measured-best gemm1 body (BK=32, [128][40]).
// LDS: xs 34.8 KB with As/Bs unioned inside -> 4 blocks/CU.
__global__ __launch_bounds__(256) void xy_gemm(
        const unsigned short* __restrict__ aggNF, const unsigned short* __restrict__ W1bt,
        const float* __restrict__ b1, const unsigned short* __restrict__ Zt,
        float* __restrict__ Y, int M) {
    __shared__ unsigned short smem[128 * 136];           // 34816 B
    unsigned short (*As)[40]  = (unsigned short (*)[40])smem;          // 128x40
    unsigned short (*Bs)[40]  = (unsigned short (*)[40])(smem + 5120); // 128x40
    unsigned short (*xs)[136] = (unsigned short (*)[136])smem;         // reuse
    int bswz = blockIdx.x;
    int xcd  = bswz & 7;
    int grp  = bswz >> 3;
    int slot = grp >> 3;
    int nidx = grp & 7;
    int midx = xcd + slot * 8;
    if (midx >= (M + 127) / 128) return;
    int m0 = midx * 128;
    int n0 = nidx * 128;
    int t = threadIdx.x;
    int wave = t >> 6, lane = t & 63;
    int lm = lane & 15, lq = lane >> 4;
    floatx4 acc[2][8] = {};
    // ---- GEMM1: x_tile = aggNF[m0:,:] @ W1bt[n0:,:]^T   (K=320, BK=32) ----
    for (int k0 = 0; k0 < KPAD1; k0 += 32) {
        #pragma unroll
        for (int p = 0; p < 2; p++) {        // A tile: 128x32 shorts = 512 uint4
            int idx = p * 256 + t;
            int r = idx >> 2, c8 = (idx & 3) * 8;
            uint4 v = make_uint4(0, 0, 0, 0);
            int gm = m0 + r;
            if (gm < M) v = *(const uint4*)(aggNF + (long)gm * KPAD1 + k0 + c8);
            *(uint4*)&As[r][c8] = v;
        }
        #pragma unroll
        for (int p = 0; p < 2; p++) {        // B tile: 128x32 shorts = 512 uint4
            int idx = p * 256 + t;
            int r = idx >> 2, c8 = (idx & 3) * 8;
            uint4 v = *(const uint4*)(W1bt + (long)(n0 + r) * KPAD1 + k0 + c8);
            *(uint4*)&Bs[r][c8] = v;
        }
        __syncthreads();
        short8 a[2], b[8];
        #pragma unroll
        for (int rt = 0; rt < 2; rt++)
            a[rt] = *(const short8*)&As[wave * 32 + rt * 16 + lm][lq * 8];
        #pragma unroll
        for (int ct = 0; ct < 8; ct++)
            b[ct] = *(const short8*)&Bs[ct * 16 + lm][lq * 8];
        #pragma unroll
        for (int rt = 0; rt < 2; rt++)
            #pragma unroll
            for (int ct = 0; ct < 8; ct++)
                acc[rt][ct] = __builtin_amdgcn_mfma_f32_16x16x32_bf16(
                    a[rt], b[ct], acc[rt][ct], 0, 0, 0);
        __syncthreads();   // all waves done with As/Bs -> safe to reuse as xs
    }
    // ---- epilogue 1: bias + leaky, C-layout -> xs (A-frag-readable) ----
    #pragma unroll
    for (int ct = 0; ct < 8; ct++) {
        int col = ct * 16 + lm;
        float bv = b1[n0 + col];
        #pragma unroll
        for (int rt = 0; rt < 2; rt++) {
            #pragma unroll
            for (int r = 0; r < 4; r++) {
                float v = acc[rt][ct][r] + bv;
                v = v >= 0.f ? v : 0.2f * v;
                xs[wave * 32 + rt * 16 + lq * 4 + r][col] = f2bf(v);
            }
        }
    }
    __syncthreads();
    // ---- GEMM2: Y[m0:,:] += x_tile @ Zt[:, n0:n0+128]^T ----
    floatx4 yacc[2][4] = {};
    #pragma unroll
    for (int kk = 0; kk < 4; kk++) {
        short8 a0 = *(const short8*)&xs[wave * 32 + lm][kk * 32 + lq * 8];
        short8 a1 = *(const short8*)&xs[wave * 32 + 16 + lm][kk * 32 + lq * 8];
        #pragma unroll
        for (int bt = 0; bt < 4; bt++) {
            short8 b = *(const short8*)(Zt + (long)(bt * 16 + lm) * HIDDIM
                                            + n0 + kk * 32 + lq * 8);
            yacc[0][bt] = __builtin_amdgcn_mfma_f32_16x16x32_bf16(a0, b, yacc[0][bt], 0, 0, 0);
            yacc[1][bt] = __builtin_amdgcn_mfma_f32_16x16x32_bf16(a1, b, yacc[1][bt], 0, 0, 0);
        }
    }
    #pragma unroll
    for (int rt = 0; rt < 2; rt++) {
        #pragma unroll
        for (int bt = 0; bt < 4; bt++) {
            #pragma unroll
            for (int r = 0; r < 4; r++) {
                int gm = m0 + wave * 32 + rt * 16 + lq * 4 + r;
                if (gm < M) atomicAdd(&Y[(long)gm * 64 + bt * 16 + lm], yacc[rt][bt][r]);
            }
        }
    }
}

// ---------------- out[b,d] = sum_{e:dst=d} w*Y[src,b] + c[b] ------------------
__global__ __launch_bounds__(256) void outagg_kernel(const float* __restrict__ Y,
        const int* __restrict__ row_start, const int* __restrict__ src_s,
        const float* __restrict__ wnrm_s, const float* __restrict__ c,
        float* __restrict__ out, int N) {
    __shared__ float tile[4][68];
    int d0 = blockIdx.x * 4;
    int t = threadIdx.x;
    int wave = t >> 6, lane = t & 63;
    int d = d0 + wave;
    int s0 = row_start[d], s1 = row_start[d + 1];
    float acc = 0.f;
    for (int base = s0; base < s1; base += 64) {
        int m = s1 - base; if (m > 64) m = 64;
        int   src_l = (lane < m) ? src_s[base + lane]  : 0;
        float w_l   = (lane < m) ? wnrm_s[base + lane] : 0.f;
        int sj = __shfl(src_l, 0);
        float wj = __shfl(w_l, 0);
        float yv = Y[(long)sj * 64 + lane];
        for (int j = 0; j < m; j++) {
            float yn = 0.f, wn = 0.f;
            if (j + 1 < m) {
                int sn = __shfl(src_l, j + 1);
                wn = __shfl(w_l, j + 1);
                yn = Y[(long)sn * 64 + lane];
            }
            acc += wj * yv;
            yv = yn; wj = wn;
        }
    }
    tile[wave][lane] = acc + c[lane];
    __syncthreads();
    int b = t >> 2, j = t & 3;
    out[(long)b * N + d0 + j] = tile[j][b];
}

extern "C" void kernel_launch(void* const* d_in, const int* in_sizes, int n_in,
                              void* d_out, int out_size, void* d_ws, size_t ws_size,
                              hipStream_t stream) {
    const float* img_feat      = (const float*)d_in[0];
    const float* node_features = (const float*)d_in[1];
    const int*   edge_src      = (const int*)d_in[2];
    const int*   edge_dst      = (const int*)d_in[3];
    const float* edge_weight   = (const float*)d_in[4];
    const float* W1            = (const float*)d_in[5];
    const float* b1            = (const float*)d_in[6];
    const float* W2            = (const float*)d_in[7];
    const float* b2            = (const float*)d_in[8];
    float* out = (float*)d_out;

    const int N = NNODES, E = NEDGES;

    char* ws = (char*)d_ws;
    size_t off = 0;
    auto alloc = [&](size_t bytes) -> void* {
        void* p = ws + off;
        off = (off + bytes + 255) & ~(size_t)255;
        return p;
    };
    // ---- zero-initialized region (single memset) ----
    float*          deg       = (float*)alloc((size_t)N * 4);
    int*            cnt       = (int*)alloc((size_t)N * 4);
    int*            cursor    = (int*)alloc((size_t)N * 4);
    float*          Ztf       = (float*)alloc((size_t)BQ * HIDDIM * 4);
    float*          Y         = (float*)alloc((size_t)N * BQ * 4);
    size_t zero_bytes = off;
    // ---- rest ----
    int*            row_start = (int*)alloc((size_t)(N + 1) * 4);
    int*            src_s     = (int*)alloc((size_t)E * 4);
    float*          wnrm_s    = (float*)alloc((size_t)E * 4);
    unsigned short* aggNF     = (unsigned short*)alloc((size_t)N * KPAD1 * 2);
    unsigned short* W1bt      = (unsigned short*)alloc((size_t)HIDDIM * KPAD1 * 2);
    unsigned short* W2b       = (unsigned short*)alloc((size_t)HIDDIM * OUTDIM * 2);
    unsigned short* imgb      = (unsigned short*)alloc((size_t)BQ * OUTDIM * 2);
    unsigned short* nfb       = (unsigned short*)alloc((size_t)N * FTEXT * 2);
    unsigned short* Zt        = (unsigned short*)alloc((size_t)BQ * HIDDIM * 2);
    float*          cvec      = (float*)alloc((size_t)BQ * 4);

    hipMemsetAsync(ws, 0, zero_bytes, stream);

    int eb = (E + 255) / 256;
    degcnt_kernel<<<eb, 256, 0, stream>>>(edge_dst, edge_weight, deg, cnt, E);
    scan_kernel<<<1, 1024, 0, stream>>>(cnt, row_start, N);
    fill_kernel<<<eb, 256, 0, stream>>>(edge_dst, edge_src, edge_weight, deg, row_start,
                                        cursor, src_s, wnrm_s, E);

    cvt_all_kernel<<<(W1N + (N1F4 + N2F4 + N3F4) + 255) / 256, 256, 0, stream>>>(
        W1, W1bt, W2, W2b, img_feat, imgb, node_features, nfb);

    // Ztf = img @ W2^T  [64 x 1024]  (MFMA, split-K=13, fp32 atomic)
    mfma_gemm<0, 0, 1, 64><<<dim3(HIDDIM / 64, 1, 13), 256, 0, stream>>>(
        imgb, W2b, nullptr, Ztf, BQ, HIDDIM, OUTDIM, HIDDIM);
    ztcvec_kernel<<<(BQ * HIDDIM) / 256 + BQ, 256, 0, stream>>>(Ztf, Zt, img_feat, b2, cvec);

    // aggNF = bf16(A @ nfb), k-padded
    aggnf_kernel<<<N / 4, 256, 0, stream>>>(nfb, row_start, src_s, wnrm_s, aggNF);

    // FUSED: Y += leaky(aggNF @ W1 + b1) @ Zt^T   (x on-chip; XCD-swizzled grid)
    // 1280 = 8 xcd * 8 n * 20 m-slots (24 blocks early-exit at m>=157)
    xy_gemm<<<1280, 256, 0, stream>>>(aggNF, W1bt, b1, Zt, Y, N);

    outagg_kernel<<<N / 4, 256, 0, stream>>>(Y, row_start, src_s, wnrm_s, cvec, out, N);
}